// Round 11
// baseline (62.974 us; speedup 1.0000x reference)
//
#include <hip/hip_runtime.h>
#include <hip/hip_bf16.h>

// SPP patch extraction, fused single-launch.
// feat (512,48,48) fp32; scales {4,6,8,10,12,14,16}, stride-2 SxS windows,
// adaptive max pool 7x7 -> (ny*nx, 512*49) per scale, concatenated.
//
// R11 = R10 minus the owb LDS round-trip. The owb staging existed only to
// make stores b128-coalesced, but the store pipe is bytes-bound, not
// instruction-bound, and it cost 568 MB of LDS traffic (P3 writes + P4
// reads). Now P3 keeps its 7 outputs in registers and stores directly:
// lane l owns output bytes [l*28, l*28+28) of the patch chunk -> 7 b32
// stores; the wave's 7 store instrs jointly cover one dense 1568B run and
// L2 (write-back, byte enables) merges them into full lines.
//  P2: rp[row=c*7+py][x] = y-binned max (float2), ONE barrier.
//  Emit: wave-autonomous over patches ix = wv, wv+4, ...; no LDS writes,
//  no fences, no barriers; stores stream continuously.
// LDS = rp only (11.2 KB); heavy-first scale ordering for tail balance.

#define HW 48
#define CSTR (HW * HW)   // 2304
#define POOL 7
#define PE 25088         // 512*49 elems per patch
#define CH 8             // channels per block
#define RPS 50           // rp row stride (floats)

constexpr int cdiv7(int x) { return (x + 6) / 7; }
constexpr int nyf(int S) { return (HW - S) / 2 + 1; }
constexpr int max_bin(int S) {
    int m = 0;
    for (int i = 0; i < POOL; ++i) {
        int a = (i * S) / POOL, b = cdiv7((i + 1) * S);
        if (b - a > m) m = b - a;
    }
    return m;
}

template <int S>
__device__ __forceinline__ void run_scale(int b, const float* __restrict__ feat,
                                          float* __restrict__ outp, float* rp) {
    constexpr int NX = nyf(S);
    constexpr int MB = max_bin(S);
    const int tid = threadIdx.x;
    const int iy = b >> 6;           // 64 chunks
    const int c0 = (b & 63) * CH;
    const int y0 = iy * 2;

    // ---- P2: rp[row][x] = y-binned max, float2, direct from cache ----
    const float* fb = feat + (size_t)c0 * CSTR + y0 * HW;
    for (int t = tid; t < CH * POOL * (HW / 2); t += 256) {   // 1344
        int c = t / (POOL * 24);
        int rem = t - c * (POOL * 24);
        int py = rem / 24;
        int xl = rem - py * 24;                               // x = 2*xl
        int ay = (py * S) / POOL;
        int szy = cdiv7((py + 1) * S) - ay;
        const float* wb = fb + c * CSTR + ay * HW + 2 * xl;
        float2 m = *(const float2*)wb;
#pragma unroll
        for (int r = 1; r < MB; ++r) {
            float2 v = *(const float2*)(wb + min(r, szy - 1) * HW);
            m.x = fmaxf(m.x, v.x);
            m.y = fmaxf(m.y, v.y);
        }
        *(float2*)(rp + (c * POOL + py) * RPS + 2 * xl) = m;
    }
    __syncthreads();                 // the only barrier

    // ---- wave-autonomous emit, direct register->global stores ----
    const int wv = tid >> 6;
    const int lane = tid & 63;
    float* obase = outp + (size_t)iy * NX * PE + (size_t)c0 * 49;

    for (int ix = wv; ix < NX; ix += 4) {
        if (lane < 56) {
            const float* v = rp + lane * RPS + 2 * ix;   // 8B-aligned
            float x[S];
#pragma unroll
            for (int k = 0; k < S / 2; ++k) {
                float2 p = *(const float2*)(v + 2 * k);
                x[2 * k] = p.x;
                x[2 * k + 1] = p.y;
            }
            float* od = obase + (size_t)ix * PE + lane * 7;  // 28B run/lane
#pragma unroll
            for (int px = 0; px < POOL; ++px) {
                int ax = (px * S) / POOL;                // compile-time
                int bx = cdiv7((px + 1) * S);
                float m = x[ax];
#pragma unroll
                for (int k = ax + 1; k < bx; ++k) m = fmaxf(m, x[k]);
                od[px] = m;
            }
        }
    }
}

__global__ __launch_bounds__(256) void spp_fused(const float* __restrict__ feat,
                                                 float* __restrict__ out) {
    __shared__ float rp[CH * POOL * RPS];        // 11.2 KB
    int b = blockIdx.x;
    // Heavy-first: S=16,14,12,10,8,6,4. Output offsets stay in scale order.
    if (b < 1088)      run_scale<16>(b,         feat, out + (size_t)2539 * PE, rp);
    else if (b < 2240) run_scale<14>(b - 1088,  feat, out + (size_t)2215 * PE, rp);
    else if (b < 3456) run_scale<12>(b - 2240,  feat, out + (size_t)1854 * PE, rp);
    else if (b < 4736) run_scale<10>(b - 3456,  feat, out + (size_t)1454 * PE, rp);
    else if (b < 6080) run_scale<8>(b - 4736,   feat, out + (size_t)1013 * PE, rp);
    else if (b < 7488) run_scale<6>(b - 6080,   feat, out + (size_t)529  * PE, rp);
    else               run_scale<4>(b - 7488,   feat, out,                     rp);
}

extern "C" void kernel_launch(void* const* d_in, const int* in_sizes, int n_in,
                              void* d_out, int out_size, void* d_ws, size_t ws_size,
                              hipStream_t stream) {
    const float* feat = (const float*)d_in[0];
    float* out = (float*)d_out;
    spp_fused<<<8960, 256, 0, stream>>>(feat, out);
}

// Round 12
// 54.472 us; speedup vs baseline: 1.1561x; 1.1561x over previous
//
#include <hip/hip_runtime.h>
#include <hip/hip_bf16.h>

// SPP patch extraction, fused single-launch.
// feat (512,48,48) fp32; scales {4,6,8,10,12,14,16}, stride-2 SxS windows,
// adaptive max pool 7x7 -> (ny*nx, 512*49) per scale, concatenated.
//
// R12 = R10 (owb staging + b128 stores — R11 proved direct strided b32
// stores cost ~6x line-transactions) + PATCH-PAIRING in the emit loop:
// adjacent patches share all but 2 window columns, so one b64 read block
// of S+2 floats per lane feeds TWO patches' x-pools (44% fewer P3 LDS
// reads at S=16). myout slice reused sequentially per patch (wave-ordered
// DS ops -> compiler fences only, no barriers).
//  P2: rp[row=c*7+py][x] = y-binned max (float2 loads), ONE barrier.
//  Emit: wave-autonomous over patch pairs (2p, 2p+1), p = wv, wv+4, ...

#define HW 48
#define CSTR (HW * HW)   // 2304
#define POOL 7
#define PE 25088         // 512*49 elems per patch
#define CH 8             // channels per block
#define RPS 50           // rp row stride (floats)

constexpr int cdiv7(int x) { return (x + 6) / 7; }
constexpr int nyf(int S) { return (HW - S) / 2 + 1; }
constexpr int max_bin(int S) {
    int m = 0;
    for (int i = 0; i < POOL; ++i) {
        int a = (i * S) / POOL, b = cdiv7((i + 1) * S);
        if (b - a > m) m = b - a;
    }
    return m;
}

template <int S>
__device__ __forceinline__ void run_scale(int b, const float* __restrict__ feat,
                                          float* __restrict__ outp,
                                          float* rp, float* owb) {
    constexpr int NX = nyf(S);
    constexpr int MB = max_bin(S);
    const int tid = threadIdx.x;
    const int iy = b >> 6;           // 64 chunks
    const int c0 = (b & 63) * CH;
    const int y0 = iy * 2;

    // ---- P2: rp[row][x] = y-binned max, float2, direct from cache ----
    const float* fb = feat + (size_t)c0 * CSTR + y0 * HW;
    for (int t = tid; t < CH * POOL * (HW / 2); t += 256) {   // 1344
        int c = t / (POOL * 24);
        int rem = t - c * (POOL * 24);
        int py = rem / 24;
        int xl = rem - py * 24;                               // x = 2*xl
        int ay = (py * S) / POOL;
        int szy = cdiv7((py + 1) * S) - ay;
        const float* wb = fb + c * CSTR + ay * HW + 2 * xl;
        float2 m = *(const float2*)wb;
#pragma unroll
        for (int r = 1; r < MB; ++r) {
            float2 v = *(const float2*)(wb + min(r, szy - 1) * HW);
            m.x = fmaxf(m.x, v.x);
            m.y = fmaxf(m.y, v.y);
        }
        *(float2*)(rp + (c * POOL + py) * RPS + 2 * xl) = m;
    }
    __syncthreads();                 // the only barrier

    // ---- wave-autonomous emit over patch pairs ----
    const int wv = tid >> 6;
    const int lane = tid & 63;
    float* myout = owb + wv * 392;   // private per-wave staging
    float* obase = outp + (size_t)iy * NX * PE + (size_t)c0 * 49;

    auto storeout = [&](int ix) {
        float* od = obase + (size_t)ix * PE;
        float4 vv = *(const float4*)(myout + 4 * lane);
        *(float4*)(od + 4 * lane) = vv;
        int k2 = lane + 64;
        if (k2 < 98) {
            float4 v2 = *(const float4*)(myout + 4 * k2);
            *(float4*)(od + 4 * k2) = v2;
        }
    };

    for (int p = wv; 2 * p < NX; p += 4) {
        const int ix0 = 2 * p;
        float x[S + 2];
        if (lane < 56) {
            // one read block covers patches ix0 and ix0+1 (cols 2ix0..2ix0+S+1)
            // tail cols 48-49 stay inside rp's RPS=50 padding.
            const float* v = rp + lane * RPS + 2 * ix0;   // 8B-aligned
#pragma unroll
            for (int k = 0; k < S / 2 + 1; ++k) {
                float2 q = *(const float2*)(v + 2 * k);
                x[2 * k] = q.x;
                x[2 * k + 1] = q.y;
            }
            float* ob = myout + lane * 7;                 // output order
#pragma unroll
            for (int px = 0; px < POOL; ++px) {
                int ax = (px * S) / POOL;                 // compile-time
                int bx = cdiv7((px + 1) * S);
                float m = x[ax];
#pragma unroll
                for (int k = ax + 1; k < bx; ++k) m = fmaxf(m, x[k]);
                ob[px] = m;
            }
        }
        asm volatile("" ::: "memory");  // P3 writes before P4 reads
        storeout(ix0);
        asm volatile("" ::: "memory");  // P4 reads before next P3 writes
        if (ix0 + 1 < NX) {
            if (lane < 56) {
                float* ob = myout + lane * 7;
#pragma unroll
                for (int px = 0; px < POOL; ++px) {
                    int ax = (px * S) / POOL;
                    int bx = cdiv7((px + 1) * S);
                    float m = x[2 + ax];
#pragma unroll
                    for (int k = ax + 1; k < bx; ++k) m = fmaxf(m, x[2 + k]);
                    ob[px] = m;
                }
            }
            asm volatile("" ::: "memory");
            storeout(ix0 + 1);
            asm volatile("" ::: "memory");
        }
    }
}

__global__ __launch_bounds__(256) void spp_fused(const float* __restrict__ feat,
                                                 float* __restrict__ out) {
    __shared__ float rp[CH * POOL * RPS];        // 11.2 KB
    __shared__ __align__(16) float owb[4 * 392]; // 6.3 KB (per-wave slices)
    int b = blockIdx.x;
    // Heavy-first: S=16,14,12,10,8,6,4. Output offsets stay in scale order.
    if (b < 1088)      run_scale<16>(b,         feat, out + (size_t)2539 * PE, rp, owb);
    else if (b < 2240) run_scale<14>(b - 1088,  feat, out + (size_t)2215 * PE, rp, owb);
    else if (b < 3456) run_scale<12>(b - 2240,  feat, out + (size_t)1854 * PE, rp, owb);
    else if (b < 4736) run_scale<10>(b - 3456,  feat, out + (size_t)1454 * PE, rp, owb);
    else if (b < 6080) run_scale<8>(b - 4736,   feat, out + (size_t)1013 * PE, rp, owb);
    else if (b < 7488) run_scale<6>(b - 6080,   feat, out + (size_t)529  * PE, rp, owb);
    else               run_scale<4>(b - 7488,   feat, out,                     rp, owb);
}

extern "C" void kernel_launch(void* const* d_in, const int* in_sizes, int n_in,
                              void* d_out, int out_size, void* d_ws, size_t ws_size,
                              hipStream_t stream) {
    const float* feat = (const float*)d_in[0];
    float* out = (float*)d_out;
    spp_fused<<<8960, 256, 0, stream>>>(feat, out);
}